// Round 1
// baseline (250.855 us; speedup 1.0000x reference)
//
#include <hip/hip_runtime.h>

#define HH 128
#define WW 128
#define HWSZ (128*128)
#define CC 64
#define OO 64
#define BB 4

// ws layout (floats):
//   off    : [B][18][H][W]   at 0        size 4*18*16384 = 1179648
//   wdef_t : [576][64]       at 1179648  size 36864
//   woff_t : [576][24]       at 1216512  size 13824 (cols 18..23 zero pad)

__global__ void k_transpose(const float* __restrict__ w_off,
                            const float* __restrict__ w_def,
                            float* __restrict__ woff_t,
                            float* __restrict__ wdef_t) {
    int i = blockIdx.x * 256 + threadIdx.x;
    if (i < 576 * 64) {
        int row = i >> 6, o = i & 63;            // row = c*9+kk
        wdef_t[i] = w_def[o * 576 + row];
    }
    int j = i - 576 * 64;
    if (j >= 0 && j < 576 * 24) {
        int row = j / 24, col = j - row * 24;    // row = c*9+r
        woff_t[j] = (col < 18) ? w_off[col * 576 + row] : 0.f;
    }
}

__launch_bounds__(128)
__global__ void k_offconv(const float* __restrict__ x,
                          const float* __restrict__ woff_t,
                          const float* __restrict__ b_off,
                          float* __restrict__ off) {
    __shared__ float wl[576 * 24];               // 54 KB
    for (int i = threadIdx.x; i < 576 * 24; i += 128) wl[i] = woff_t[i];
    __syncthreads();

    int p = blockIdx.x * 128 + threadIdx.x;      // pixel id
    int b = p >> 14;
    int hw = p & 16383;
    int h = hw >> 7, w = hw & 127;

    const float* xb = x + b * (CC * HWSZ);

    float acc[18];
    #pragma unroll
    for (int j = 0; j < 18; ++j) acc[j] = b_off[j];

    for (int c = 0; c < CC; ++c) {
        const float* xc = xb + c * HWSZ;
        #pragma unroll
        for (int r = 0; r < 9; ++r) {
            int ry = r / 3 - 1, rx = r - (r / 3) * 3 - 1;
            int yy = h + ry, xx = w + rx;
            float xv = 0.f;
            if ((unsigned)yy < HH && (unsigned)xx < WW) xv = xc[yy * WW + xx];
            const float* wr = &wl[(c * 9 + r) * 24];
            #pragma unroll
            for (int q = 0; q < 4; ++q) {
                float4 wv = *(const float4*)(wr + q * 4);
                acc[q*4+0] += xv * wv.x;
                acc[q*4+1] += xv * wv.y;
                acc[q*4+2] += xv * wv.z;
                acc[q*4+3] += xv * wv.w;
            }
            float2 wv2 = *(const float2*)(wr + 16);
            acc[16] += xv * wv2.x;
            acc[17] += xv * wv2.y;
        }
    }

    float* ob = off + b * (18 * HWSZ) + h * WW + w;
    #pragma unroll
    for (int j = 0; j < 18; ++j) {
        float v = fminf(fmaxf(acc[j], -1.f), 1.f);
        ob[j * HWSZ] = v;
    }
}

__launch_bounds__(128)
__global__ void k_deform(const float* __restrict__ x,
                         const float* __restrict__ off,
                         const float* __restrict__ wdef_t,
                         const float* __restrict__ b_def,
                         float* __restrict__ out) {
    int w = threadIdx.x;                 // 0..127
    int half = blockIdx.x & 1;           // o-half (block-uniform -> scalar weights)
    int bh = blockIdx.x >> 1;            // b*128 + h
    int b = bh >> 7, h = bh & 127;
    int obase = half * 32;

    const float* xb = x + b * (CC * HWSZ);
    const float* offb = off + b * (18 * HWSZ) + h * WW + w;

    float acc[32];
    #pragma unroll
    for (int i = 0; i < 32; ++i) acc[i] = 0.f;

    for (int kk = 0; kk < 9; ++kk) {
        float dy = offb[(2 * kk) * HWSZ];
        float dx = offb[(2 * kk + 1) * HWSZ];
        int ky = kk / 3 - 1, kx = kk - (kk / 3) * 3 - 1;
        float py = (float)(h + ky) + dy;
        float px = (float)(w + kx) + dx;
        float y0f = floorf(py), x0f = floorf(px);
        float ly = py - y0f, lx = px - x0f;
        int y0 = (int)y0f, x0 = (int)x0f;
        int y1 = y0 + 1, x1 = x0 + 1;
        float vy0 = ((unsigned)y0 < HH) ? 1.f : 0.f;
        float vy1 = ((unsigned)y1 < HH) ? 1.f : 0.f;
        float vx0 = ((unsigned)x0 < WW) ? 1.f : 0.f;
        float vx1 = ((unsigned)x1 < WW) ? 1.f : 0.f;
        float w00 = (1.f - ly) * (1.f - lx) * vy0 * vx0;
        float w01 = (1.f - ly) * lx * vy0 * vx1;
        float w10 = ly * (1.f - lx) * vy1 * vx0;
        float w11 = ly * lx * vy1 * vx1;
        int yc0 = min(max(y0, 0), HH - 1), yc1 = min(max(y1, 0), HH - 1);
        int xc0 = min(max(x0, 0), WW - 1), xc1 = min(max(x1, 0), WW - 1);
        int i00 = yc0 * WW + xc0, i01 = yc0 * WW + xc1;
        int i10 = yc1 * WW + xc0, i11 = yc1 * WW + xc1;

        const float* wrow = wdef_t + kk * 64 + obase;   // +576 per c
        const float* xc = xb;
        for (int c = 0; c < CC; ++c) {
            float s = xc[i00] * w00 + xc[i01] * w01 + xc[i10] * w10 + xc[i11] * w11;
            const float4* w4 = (const float4*)(wrow);
            #pragma unroll
            for (int q = 0; q < 8; ++q) {
                float4 wv = w4[q];
                acc[q*4+0] += s * wv.x;
                acc[q*4+1] += s * wv.y;
                acc[q*4+2] += s * wv.z;
                acc[q*4+3] += s * wv.w;
            }
            xc += HWSZ;
            wrow += 576;
        }
    }

    float* ob = out + b * (OO * HWSZ) + h * WW + w;
    #pragma unroll
    for (int i = 0; i < 32; ++i)
        ob[(obase + i) * HWSZ] = acc[i] + b_def[obase + i];
}

extern "C" void kernel_launch(void* const* d_in, const int* in_sizes, int n_in,
                              void* d_out, int out_size, void* d_ws, size_t ws_size,
                              hipStream_t stream) {
    const float* x     = (const float*)d_in[0];
    const float* w_off = (const float*)d_in[1];
    const float* b_off = (const float*)d_in[2];
    const float* w_def = (const float*)d_in[3];
    const float* b_def = (const float*)d_in[4];
    float* out = (float*)d_out;

    float* ws     = (float*)d_ws;
    float* off    = ws;                      // 1179648 floats
    float* wdef_t = ws + 1179648;            // 36864
    float* woff_t = ws + 1179648 + 36864;    // 13824

    k_transpose<<<198, 256, 0, stream>>>(w_off, w_def, woff_t, wdef_t);
    k_offconv<<<512, 128, 0, stream>>>(x, woff_t, b_off, off);
    k_deform<<<1024, 128, 0, stream>>>(x, off, wdef_t, b_def, out);
}